// Round 5
// baseline (814.794 us; speedup 1.0000x reference)
//
#include <hip/hip_runtime.h>
#include <stdint.h>
#include <stddef.h>

typedef __attribute__((ext_vector_type(8))) short bf16x8;
typedef __attribute__((ext_vector_type(4))) float f32x4;
typedef __attribute__((ext_vector_type(8))) unsigned short u16x8;
typedef __attribute__((ext_vector_type(4))) unsigned short u16x4;
typedef __attribute__((ext_vector_type(2))) unsigned short u16x2;

#define DEVINL __device__ __forceinline__

DEVINL unsigned short f2b(float x){
  union { float f; unsigned int u; } v; v.f = x;
  return (unsigned short)((v.u + 0x7FFFu + ((v.u >> 16) & 1u)) >> 16);
}
DEVINL float b2f(unsigned short h){
  union { float f; unsigned int u; } v; v.u = ((unsigned int)h) << 16;
  return v.f;
}

DEVINL void gl_lds16(void* g, void* lds){
  __builtin_amdgcn_global_load_lds(
      (__attribute__((address_space(1))) void*)g,
      (__attribute__((address_space(3))) void*)lds, 16, 0, 0);
}

// ---------------------------------------------------------------------------
// prep: weights -> bf16 [n][k], slice-major layout:
//   slice i block (393216 elems): {m1w2, m2w2, wq(/16), wk, wv, wo} each 256x256
//   (wq,wk adjacent -> one N=512 GEMM). Then tdT (512x256). BN fold.
// ---------------------------------------------------------------------------
__global__ __launch_bounds__(256) void prep_k(
    const float* __restrict__ m1w2, const float* __restrict__ m2w2,
    const float* __restrict__ wqp,  const float* __restrict__ wkp,
    const float* __restrict__ wvp,  const float* __restrict__ wop,
    const float* __restrict__ tdw,  const float* __restrict__ tdb,
    const float* __restrict__ bng,  const float* __restrict__ bnb,
    const float* __restrict__ bnm,  const float* __restrict__ bnv,
    unsigned short* __restrict__ wT, float* __restrict__ bns, float* __restrict__ bnt)
{
  int idx = blockIdx.x * 256 + threadIdx.x;
  if (idx < 786432){
    int i   = idx / 393216;
    int rem = idx - i*393216;
    int mat = rem >> 16;
    int eb  = rem & 65535;
    int n = eb >> 8, kx = eb & 255;
    const float* src; float sc = 1.0f;
    if      (mat == 0) src = m1w2;
    else if (mat == 1) src = m2w2;
    else if (mat == 2){ src = wqp; sc = 0.0625f; }
    else if (mat == 3) src = wkp;
    else if (mat == 4) src = wvp;
    else               src = wop;
    wT[idx] = f2b(src[i*65536 + kx*256 + n] * sc);
  } else if (idx < 917504){
    int e = idx - 786432;
    int n = e >> 8, kx = e & 255;
    wT[786432 + e] = f2b(tdw[kx*512 + n]);
  } else if (idx < 918016){
    int c = idx - 917504;
    float s = bng[c] * rsqrtf(bnv[c] + 1e-5f);
    bns[c] = s;
    bnt[c] = (tdb[c] - bnm[c]) * s + bnb[c];
  }
}

// ---------------------------------------------------------------------------
// geomG: per 256 points, compute G0 (cs=16) and G1 (cs=64): (lp.x,lp.y,lp.z,|lp|)
// ---------------------------------------------------------------------------
__global__ __launch_bounds__(256) void geomG_k(
    const float* __restrict__ pos, float* __restrict__ G0, float* __restrict__ G1)
{
  __shared__ float P[256][3];
  const int t = threadIdx.x;
  const int base = blockIdx.x * 256;
  P[t][0] = pos[(size_t)(base+t)*3 + 0];
  P[t][1] = pos[(size_t)(base+t)*3 + 1];
  P[t][2] = pos[(size_t)(base+t)*3 + 2];
  __syncthreads();
  const int b16 = t & ~15;
  float cx=0.f, cy=0.f, cz=0.f;
  for (int j = 0; j < 16; j++){ cx += P[b16+j][0]; cy += P[b16+j][1]; cz += P[b16+j][2]; }
  cx *= 0.0625f; cy *= 0.0625f; cz *= 0.0625f;
  const int b64 = t & ~63;
  float dx=0.f, dy=0.f, dz=0.f;
  for (int j = 0; j < 64; j++){ dx += P[b64+j][0]; dy += P[b64+j][1]; dz += P[b64+j][2]; }
  dx *= 0.015625f; dy *= 0.015625f; dz *= 0.015625f;
  float x = P[t][0], y = P[t][1], z = P[t][2];
  float a0 = x-cx, a1 = y-cy, a2 = z-cz;
  float e0 = x-dx, e1 = y-dy, e2 = z-dz;
  float4 g0; g0.x=a0; g0.y=a1; g0.z=a2; g0.w=sqrtf(a0*a0+a1*a1+a2*a2);
  float4 g1; g1.x=e0; g1.y=e1; g1.z=e2; g1.w=sqrtf(e0*e0+e1*e1+e2*e2);
  *(float4*)(G0 + (size_t)(base+t)*4) = g0;
  *(float4*)(G1 + (size_t)(base+t)*4) = g1;
}

// ---------------------------------------------------------------------------
// rgemm: out[M, ldc] (bf16 tile 128 x 256 per WG) = Astage @ Wt[n][k]^T.
//  - PROD: A-tile computed in-prologue as relu(G@w1+b1) from G[M][4] (hk rows)
//    else A staged from global bf16 via global_load_lds (XOR-swizzled).
//  - K-loop barrier-free: B-fragments from L2 into VGPRs, depth-2 prefetch.
//  - EPI 0: out = acc (+bias) (+addend)        (addend f32 if ADD32 else bf16)
//    EPI 1: out = LN(acc + bias + addend)*p0+p1 (full 256-col row per WG)
//    EPI 2: out = relu(acc*p0+p1)               (BN fold)
// grid.y tiles N by 256: Wt += y*65536, col0 = y*256.
// ---------------------------------------------------------------------------
template<bool PROD, bool ADD32, int EPI>
__global__ __launch_bounds__(256, 2) void rgemm_k(
    const unsigned short* __restrict__ A,
    const float* __restrict__ G,
    const float* __restrict__ w1, const float* __restrict__ b1, int hk,
    const unsigned short* __restrict__ Wt,
    const float* __restrict__ bias,
    const void* __restrict__ add_,
    const float* __restrict__ p0, const float* __restrict__ p1,
    unsigned short* __restrict__ out, int ldc)
{
  __shared__ __attribute__((aligned(16))) char smem[67584];  // A-swizzle ∪ Y[128][264]
  __shared__ float Gs[128][4];
  __shared__ float red[128][4];

  const int tid  = threadIdx.x;
  const int lane = tid & 63;
  const int wave = tid >> 6;
  const int lrow = lane & 15, lq = lane >> 4;
  const int m0   = blockIdx.x * 128;
  const int col0 = blockIdx.y * 256;
  Wt += (size_t)col0 * 256;

  unsigned short* Ybuf = (unsigned short*)smem;

  // ---- stage A-tile ----
  if (PROD){
    if (tid < 128)
      *(float4*)(&Gs[tid][0]) = *(const float4*)(G + (size_t)(m0 + tid)*4);
    __syncthreads();
    const int c0 = (tid & 31) * 8;
    const int rg = tid >> 5;
    float wv0[8], wv1[8], wv2[8], wv3[8], bb[8];
#pragma unroll
    for (int j = 0; j < 8; j++){
      int c = c0 + j;
      wv0[j] = w1[c]; wv1[j] = w1[256 + c]; wv2[j] = w1[512 + c];
      wv3[j] = (hk == 4) ? w1[768 + c] : 0.f;
      bb[j]  = b1[c];
    }
#pragma unroll
    for (int i = 0; i < 16; i++){
      int r = rg*16 + i;
      float g0 = Gs[r][0], g1 = Gs[r][1], g2 = Gs[r][2], g3 = Gs[r][3];
      u16x8 o;
#pragma unroll
      for (int j = 0; j < 8; j++){
        float v = bb[j] + g0*wv0[j] + g1*wv1[j] + g2*wv2[j] + g3*wv3[j];
        o[j] = f2b(fmaxf(v, 0.f));
      }
      *(u16x8*)(smem + r*512 + (((c0 >> 3) ^ (r & 7)) << 4)) = o;
    }
  } else {
#pragma unroll
    for (int i = 0; i < 16; i++){
      int r = i*8 + (tid >> 5);
      int s = tid & 31;
      int g = s ^ (r & 7);
      gl_lds16((void*)(A + (size_t)(m0 + r)*256 + g*8), smem + i*4096 + tid*16);
    }
  }
  __syncthreads();

  // ---- K-loop: B from L2 into regs, depth-2 prefetch, no barriers ----
  const unsigned short* base[4];
#pragma unroll
  for (int nt = 0; nt < 4; nt++)
    base[nt] = Wt + (size_t)(wave*64 + nt*16 + lrow)*256 + lq*8;
  bf16x8 breg[2][4];
#pragma unroll
  for (int nt = 0; nt < 4; nt++) breg[0][nt] = *(const bf16x8*)(base[nt]);

  f32x4 acc[8][4] = {};
#pragma unroll
  for (int k = 0; k < 8; k++){
    bf16x8 af[8];
#pragma unroll
    for (int mt = 0; mt < 8; mt++){
      int row = mt*16 + lrow;
      af[mt] = *(const bf16x8*)(smem + row*512 + ((((k*4 + lq)) ^ (row & 7)) << 4));
    }
    if (k < 7){
#pragma unroll
      for (int nt = 0; nt < 4; nt++)
        breg[(k+1)&1][nt] = *(const bf16x8*)(base[nt] + (k+1)*32);
    }
#pragma unroll
    for (int mt = 0; mt < 8; mt++)
#pragma unroll
      for (int nt = 0; nt < 4; nt++)
        acc[mt][nt] = __builtin_amdgcn_mfma_f32_16x16x32_bf16(af[mt], breg[k&1][nt], acc[mt][nt], 0, 0, 0);
  }

  __syncthreads();   // A-tile dead; reuse region as Y

  // ---- fragments -> Y (bf16) ----
#pragma unroll
  for (int mt = 0; mt < 8; mt++){
#pragma unroll
    for (int nt = 0; nt < 4; nt++){
      int col = wave*64 + nt*16 + lrow;
      float sc = 1.f, sh = 0.f;
      if (EPI == 2){ sc = p0[col0 + col]; sh = p1[col0 + col]; }
      else if (bias){ sh = bias[col]; }
#pragma unroll
      for (int r = 0; r < 4; r++){
        int row = mt*16 + lq*4 + r;
        float v = acc[mt][nt][r];
        v = (EPI == 2) ? fmaxf(v*sc + sh, 0.f) : (v + sh);
        Ybuf[row*264 + col] = f2b(v);
      }
    }
  }
  __syncthreads();

  // ---- row-pass: addend / LN / store ----
  {
    const int row = tid >> 1, half = tid & 1;
    const size_t gb = (size_t)(m0 + row) * (size_t)ldc + col0 + half*128;
    if (EPI == 1){
      const unsigned short* ad = (const unsigned short*)add_;
      float sm = 0.f, sq = 0.f;
#pragma unroll
      for (int i = 0; i < 16; i++){
        int c = half*128 + i*8;
        u16x8 v = *(const u16x8*)(&Ybuf[row*264 + c]);
        u16x8 a = *(const u16x8*)(ad + (size_t)(m0 + row)*256 + c);
        u16x8 w;
#pragma unroll
        for (int j = 0; j < 8; j++){
          float y = b2f(v[j]) + b2f(a[j]);
          sm += y; sq += y*y;
          w[j] = f2b(y);
        }
        *(u16x8*)(&Ybuf[row*264 + c]) = w;
      }
      red[row][half]   = sm;
      red[row][2+half] = sq;
      __syncthreads();
      float s  = red[row][0] + red[row][1];
      float q2 = red[row][2] + red[row][3];
      float mu = s * (1.0f/256.0f);
      float var = q2 * (1.0f/256.0f) - mu*mu;
      float rs = rsqrtf(var + 1e-5f);
#pragma unroll
      for (int i = 0; i < 16; i++){
        int c = half*128 + i*8;
        u16x8 v = *(const u16x8*)(&Ybuf[row*264 + c]);
        u16x8 o;
#pragma unroll
        for (int j = 0; j < 8; j++)
          o[j] = f2b((b2f(v[j]) - mu)*rs*p0[c + j] + p1[c + j]);
        *(u16x8*)(out + gb + i*8) = o;
      }
    } else {
#pragma unroll
      for (int i = 0; i < 16; i++){
        int c = half*128 + i*8;
        u16x8 v = *(const u16x8*)(&Ybuf[row*264 + c]);
        u16x8 o;
        if (add_){
          if (ADD32){
            const float* ad = (const float*)add_;
            float4 a0 = *(const float4*)(ad + (size_t)(m0 + row)*256 + c);
            float4 a1 = *(const float4*)(ad + (size_t)(m0 + row)*256 + c + 4);
            o[0]=f2b(b2f(v[0])+a0.x); o[1]=f2b(b2f(v[1])+a0.y);
            o[2]=f2b(b2f(v[2])+a0.z); o[3]=f2b(b2f(v[3])+a0.w);
            o[4]=f2b(b2f(v[4])+a1.x); o[5]=f2b(b2f(v[5])+a1.y);
            o[6]=f2b(b2f(v[6])+a1.z); o[7]=f2b(b2f(v[7])+a1.w);
          } else {
            const unsigned short* ad = (const unsigned short*)add_;
            u16x8 a = *(const u16x8*)(ad + (size_t)(m0 + row)*256 + c);
#pragma unroll
            for (int j = 0; j < 8; j++) o[j] = f2b(b2f(v[j]) + b2f(a[j]));
          }
        } else {
          o = v;
        }
        *(u16x8*)(out + gb + i*8) = o;
      }
    }
  }
}

// ---------------------------------------------------------------------------
// Fused chunk attention (round-1 proven): per 64-row WG, q,k from stacked QK
// (stride 512), v stride 256. S=QK^T (MFMA), softmax, O=PV (MFMA).
// ---------------------------------------------------------------------------
template<int CS>
__global__ __launch_bounds__(256) void attn_k(
    const unsigned short* __restrict__ QK,
    const unsigned short* __restrict__ V,
    unsigned short* __restrict__ O)
{
  constexpr int QS = 264;
  constexpr int VS = 258;
  constexpr int SS = (CS == 64) ? 66 : 18;
  constexpr int PS = (CS == 64) ? 72 : 40;
  __shared__ __attribute__((aligned(16))) unsigned short qs[64*QS];
  __shared__ __attribute__((aligned(16))) unsigned short ks[64*QS];
  __shared__ __attribute__((aligned(16))) unsigned short vs[64*VS];
  __shared__ __attribute__((aligned(16))) float sb[64*SS];
  __shared__ __attribute__((aligned(16))) unsigned short pb[64*PS];

  const int tid  = threadIdx.x;
  const int lane = tid & 63;
  const int wave = tid >> 6;
  const int lrow = lane & 15, lq = lane >> 4;
  const int m0 = blockIdx.x * 64;

  {
    const int row = tid >> 2, cb = (tid & 3) * 64;
    const size_t gq = (size_t)(m0 + row) * 512 + cb;
    const size_t gv = (size_t)(m0 + row) * 256 + cb;
#pragma unroll
    for (int i = 0; i < 8; i++){
      u16x8 vq = *(const u16x8*)(QK + gq + i*8);
      u16x8 vk = *(const u16x8*)(QK + gq + 256 + i*8);
      u16x8 vv = *(const u16x8*)(V  + gv + i*8);
      *(u16x8*)(qs + row*QS + cb + i*8) = vq;
      *(u16x8*)(ks + row*QS + cb + i*8) = vk;
#pragma unroll
      for (int j = 0; j < 4; j++){
        u16x2 t2; t2.x = vv[2*j]; t2.y = vv[2*j+1];
        *(u16x2*)(vs + row*VS + cb + i*8 + j*2) = t2;
      }
    }
  }
  __syncthreads();

  constexpr int NT = CS / 16;
  f32x4 sacc[NT] = {};
  const int qrow = wave*16 + lrow;
#pragma unroll
  for (int kk = 0; kk < 8; kk++){
    bf16x8 aq = *(const bf16x8*)(qs + qrow*QS + kk*32 + lq*8);
#pragma unroll
    for (int nt = 0; nt < NT; nt++){
      int brow = (CS == 64) ? (nt*16 + lrow) : (wave*16 + lrow);
      bf16x8 bk = *(const bf16x8*)(ks + brow*QS + kk*32 + lq*8);
      sacc[nt] = __builtin_amdgcn_mfma_f32_16x16x32_bf16(aq, bk, sacc[nt], 0, 0, 0);
    }
  }
#pragma unroll
  for (int nt = 0; nt < NT; nt++){
#pragma unroll
    for (int r = 0; r < 4; r++){
      int srow = wave*16 + lq*4 + r;
      int scol = nt*16 + lrow;
      sb[srow*SS + scol] = sacc[nt][r];
    }
  }
  __syncthreads();

  if (tid < 64){
    float mx = -3.0e38f;
    for (int j = 0; j < CS; j++) mx = fmaxf(mx, sb[tid*SS + j]);
    float sum = 0.f;
    for (int j = 0; j < CS; j++){
      float e = __expf(sb[tid*SS + j] - mx);
      sb[tid*SS + j] = e; sum += e;
    }
    float inv = 1.0f / sum;
    for (int j = 0; j < CS; j++) pb[tid*PS + j] = f2b(sb[tid*SS + j] * inv);
    if (CS == 16){
      for (int j = 16; j < 32; j++) pb[tid*PS + j] = 0;
    }
  }
  __syncthreads();

  f32x4 oacc[4][4] = {};
  const int dbase = wave * 64;
  if (CS == 64){
#pragma unroll
    for (int kk = 0; kk < 2; kk++){
      bf16x8 ap[4];
#pragma unroll
      for (int mt = 0; mt < 4; mt++)
        ap[mt] = *(const bf16x8*)(pb + (mt*16 + lrow)*PS + kk*32 + lq*8);
#pragma unroll
      for (int nt = 0; nt < 4; nt++){
        const int d = dbase + nt*16 + lrow;
        bf16x8 bv;
#pragma unroll
        for (int j = 0; j < 8; j++)
          bv[j] = (short)vs[(kk*32 + lq*8 + j)*VS + d];
#pragma unroll
        for (int mt = 0; mt < 4; mt++)
          oacc[mt][nt] = __builtin_amdgcn_mfma_f32_16x16x32_bf16(ap[mt], bv, oacc[mt][nt], 0, 0, 0);
      }
    }
  } else {
#pragma unroll
    for (int mt = 0; mt < 4; mt++){
      bf16x8 ap = *(const bf16x8*)(pb + (mt*16 + lrow)*PS + lq*8);
#pragma unroll
      for (int nt = 0; nt < 4; nt++){
        const int d = dbase + nt*16 + lrow;
        bf16x8 bv;
#pragma unroll
        for (int j = 0; j < 8; j++){
          int kix = (lq*8 + j) & 15;
          bv[j] = (short)vs[(mt*16 + kix)*VS + d];
        }
        oacc[mt][nt] = __builtin_amdgcn_mfma_f32_16x16x32_bf16(ap, bv, oacc[mt][nt], 0, 0, 0);
      }
    }
  }

#pragma unroll
  for (int mt = 0; mt < 4; mt++){
#pragma unroll
    for (int nt = 0; nt < 4; nt++){
#pragma unroll
      for (int r = 0; r < 4; r++){
        int row = mt*16 + lq*4 + r;
        int col = dbase + nt*16 + lrow;
        qs[row*QS + col] = f2b(oacc[mt][nt][r]);
      }
    }
  }
  __syncthreads();
  {
    const int row = tid >> 2, cb = (tid & 3) * 64;
    const size_t g = (size_t)(m0 + row) * 256 + cb;
#pragma unroll
    for (int i = 0; i < 8; i++)
      *(u16x8*)(O + g + i*8) = *(const u16x8*)(qs + row*QS + cb + i*8);
  }
}

// ---------------------------------------------------------------------------
// Output: pos_ds gather + KNN max-pool over E (bf16 [65536][512]) -> fp32.
// ---------------------------------------------------------------------------
__global__ __launch_bounds__(256) void out_k(
    const unsigned short* __restrict__ F2,
    const float* __restrict__ pos,
    const int* __restrict__ fps,
    const int* __restrict__ knn,
    float* __restrict__ outp)
{
  const int p = blockIdx.x;
  const int b = p >> 11;
  const int t = threadIdx.x;
  const int* kn = knn + (size_t)p * 16;
  const int c = t * 2;
  float m1 = -3.0e38f, m2 = -3.0e38f;
  for (int j = 0; j < 16; j++){
    int idx = kn[j];
    size_t row = ((size_t)b * 8192 + idx) * 512;
    u16x2 v = *(const u16x2*)(F2 + row + c);
    m1 = fmaxf(m1, b2f(v.x));
    m2 = fmaxf(m2, b2f(v.y));
  }
  float* of = outp + 49152 + (size_t)p * 512 + c;
  float2 o; o.x = m1; o.y = m2;
  *(float2*)of = o;
  if (t < 3){
    int fi = fps[p];
    outp[(size_t)p*3 + t] = pos[((size_t)b*8192 + fi)*3 + t];
  }
}

// ---------------------------------------------------------------------------
extern "C" void kernel_launch(void* const* d_in, const int* in_sizes, int n_in,
                              void* d_out, int out_size, void* d_ws, size_t ws_size,
                              hipStream_t stream)
{
  (void)in_sizes; (void)n_in; (void)out_size; (void)ws_size;

  const float* pos  = (const float*)d_in[0];
  const float* feat = (const float*)d_in[1];
  const int*   fps  = (const int*)d_in[2];
  const int*   knn  = (const int*)d_in[3];
  const float* m1w1 = (const float*)d_in[6];
  const float* m1b1 = (const float*)d_in[7];
  const float* m1w2 = (const float*)d_in[8];
  const float* m1b2 = (const float*)d_in[9];
  const float* m2w1 = (const float*)d_in[10];
  const float* m2b1 = (const float*)d_in[11];
  const float* m2w2 = (const float*)d_in[12];
  const float* m2b2 = (const float*)d_in[13];
  const float* wq   = (const float*)d_in[14];
  const float* wk   = (const float*)d_in[15];
  const float* wv   = (const float*)d_in[16];
  const float* wo   = (const float*)d_in[17];
  const float* bo   = (const float*)d_in[18];
  const float* lng  = (const float*)d_in[19];
  const float* lnb  = (const float*)d_in[20];
  const float* tdw  = (const float*)d_in[21];
  const float* tdb  = (const float*)d_in[22];
  const float* bng  = (const float*)d_in[23];
  const float* bnb  = (const float*)d_in[24];
  const float* bnm  = (const float*)d_in[25];
  const float* bnv  = (const float*)d_in[26];

  char* ws = (char*)d_ws;
  unsigned short* wT = (unsigned short*)ws;                  // 1,835,008 B
  float* bns = (float*)(ws + 1835008);
  float* bnt = (float*)(ws + 1837056);
  float* G0  = (float*)(ws + 2*1048576);                     // 1 MB
  float* G1  = (float*)(ws + 3*1048576);                     // 1 MB
  const size_t MB = 1048576;
  unsigned short* SA = (unsigned short*)(ws + 4*MB);         // 32 MB  h_pos
  unsigned short* SB = (unsigned short*)(ws + 36*MB);        // 32 MB  h_geo / v / f1
  unsigned short* SC = (unsigned short*)(ws + 68*MB);        // 64 MB  qk / E
  unsigned short* SD = (unsigned short*)(ws + 132*MB);       // 32 MB  O
  unsigned short* SE = (unsigned short*)(ws + 164*MB);       // 32 MB  f0

  auto wtm = [&](int mat, int i){ return wT + (size_t)i*393216 + (size_t)mat*65536; };
  unsigned short* tdT = wT + 786432;

  prep_k<<<3586, 256, 0, stream>>>(m1w2, m2w2, wq, wk, wv, wo, tdw, tdb, bng, bnb, bnm, bnv,
                                   wT, bns, bnt);
  geomG_k<<<256, 256, 0, stream>>>(pos, G0, G1);

  // ================= block 0 (cs=16, slice 0, fc = feat f32) =================
  rgemm_k<true, true, 0><<<dim3(512,1), 256, 0, stream>>>(        // h_pos -> SA
      nullptr, G0, m1w1, m1b1, 4, wtm(0,0), m1b2, feat, nullptr, nullptr, SA, 256);
  rgemm_k<true, true, 0><<<dim3(512,1), 256, 0, stream>>>(        // h_geo -> SB
      nullptr, G0, m2w1 + 768, m2b1, 3, wtm(1,0), m2b2, feat, nullptr, nullptr, SB, 256);
  rgemm_k<false, false, 0><<<dim3(512,2), 256, 0, stream>>>(      // qk -> SC
      SB, nullptr, nullptr, nullptr, 0, wtm(2,0), nullptr, nullptr, nullptr, nullptr, SC, 512);
  rgemm_k<false, false, 0><<<dim3(512,1), 256, 0, stream>>>(      // v -> SB
      SA, nullptr, nullptr, nullptr, 0, wtm(4,0), nullptr, nullptr, nullptr, nullptr, SB, 256);
  attn_k<16><<<1024, 256, 0, stream>>>(SC, SB, SD);               // O -> SD
  rgemm_k<false, false, 1><<<dim3(512,1), 256, 0, stream>>>(      // f0 -> SE
      SD, nullptr, nullptr, nullptr, 0, wtm(5,0), bo, SA, lng, lnb, SE, 256);

  // ================= block 1 (cs=64, slice 1, fc = f0 bf16) =================
  rgemm_k<true, false, 0><<<dim3(512,1), 256, 0, stream>>>(       // h_pos -> SA
      nullptr, G1, m1w1 + 1024, m1b1 + 256, 4, wtm(0,1), m1b2 + 256, SE, nullptr, nullptr, SA, 256);
  rgemm_k<true, false, 0><<<dim3(512,1), 256, 0, stream>>>(       // h_geo -> SB
      nullptr, G1, m2w1 + 1536 + 768, m2b1 + 256, 3, wtm(1,1), m2b2 + 256, SE, nullptr, nullptr, SB, 256);
  rgemm_k<false, false, 0><<<dim3(512,2), 256, 0, stream>>>(      // qk -> SC
      SB, nullptr, nullptr, nullptr, 0, wtm(2,1), nullptr, nullptr, nullptr, nullptr, SC, 512);
  rgemm_k<false, false, 0><<<dim3(512,1), 256, 0, stream>>>(      // v -> SB
      SA, nullptr, nullptr, nullptr, 0, wtm(4,1), nullptr, nullptr, nullptr, nullptr, SB, 256);
  attn_k<64><<<1024, 256, 0, stream>>>(SC, SB, SD);               // O -> SD
  rgemm_k<false, false, 1><<<dim3(512,1), 256, 0, stream>>>(      // f1 -> SB
      SD, nullptr, nullptr, nullptr, 0, wtm(5,1), bo + 256, SA, lng + 256, lnb + 256, SB, 256);

  // ================= td + BN + relu -> SC (E: [65536][512]) =================
  rgemm_k<false, false, 2><<<dim3(512,2), 256, 0, stream>>>(
      SB, nullptr, nullptr, nullptr, 0, tdT, nullptr, nullptr, bns, bnt, SC, 512);

  // ================= outputs =================
  out_k<<<16384, 256, 0, stream>>>(SC, pos, fps, knn, (float*)d_out);
}